// Round 16
// baseline (355.970 us; speedup 1.0000x reference)
//
#include <hip/hip_runtime.h>

typedef __attribute__((ext_vector_type(4))) float f32x4;
typedef __attribute__((ext_vector_type(8))) __bf16 bf16x8;
typedef __attribute__((ext_vector_type(8))) unsigned short ushort8;
typedef __attribute__((ext_vector_type(4))) unsigned short ushort4v;

union UBF8 { ushort8 u; bf16x8 b; };
static __device__ __forceinline__ bf16x8 as_bf(ushort8 v) { UBF8 x; x.u = v; return x.b; }

// native f32 -> bf16 (RNE)
static __device__ __forceinline__ unsigned short f2bf(float f) {
  union { __bf16 h; unsigned short u; } v; v.h = (__bf16)f; return v.u;
}

// manual RNE (attn: exact R3/R10 codegen, 128 VGPR)
static __device__ __forceinline__ unsigned short f2bf_rn(float f) {
  union { float f; unsigned u; } v; v.f = f;
  unsigned r = v.u + 0x7fffu + ((v.u >> 16) & 1u);
  return (unsigned short)(r >> 16);
}

static __device__ __forceinline__ bf16x8 scale8(ushort8 u, float c) {
  ushort8 r;
#pragma unroll
  for (int j = 0; j < 8; j++) {
    union { unsigned u; float f; } t; t.u = ((unsigned)u[j]) << 16;
    r[j] = f2bf_rn(t.f * c);
  }
  return as_bf(r);
}

static __device__ __forceinline__ float gelu_f(float x) {
  return 0.5f * x * (1.0f + erff(x * 0.70710678118654752f));
}

typedef const __attribute__((address_space(1))) void* gas_p;
typedef __attribute__((address_space(3))) void* las_p;
static __device__ __forceinline__ void gload16(const void* g, void* l) {
  __builtin_amdgcn_global_load_lds((gas_p)g, (las_p)l, 16, 0, 0);
}

// ---------------- LayerNorm: fp32 in -> bf16 out, one row (1024) per block ----------------
__global__ __launch_bounds__(256) void ln_kernel(
    const float* __restrict__ in, const float* __restrict__ w,
    const float* __restrict__ b, unsigned short* __restrict__ out)
{
  const int row = blockIdx.x, t = threadIdx.x;
  const float4 v = *reinterpret_cast<const float4*>(in + (size_t)row * 1024 + t * 4);
  float s = v.x + v.y + v.z + v.w;
#pragma unroll
  for (int o = 32; o >= 1; o >>= 1) s += __shfl_xor(s, o);
  __shared__ float ps[4], qs[4];
  if ((t & 63) == 0) ps[t >> 6] = s;
  __syncthreads();
  const float mean = (ps[0] + ps[1] + ps[2] + ps[3]) * (1.0f / 1024.0f);
  const float cx = v.x - mean, cy = v.y - mean, cz = v.z - mean, cw = v.w - mean;
  float q = cx * cx + cy * cy + cz * cz + cw * cw;
#pragma unroll
  for (int o = 32; o >= 1; o >>= 1) q += __shfl_xor(q, o);
  if ((t & 63) == 0) qs[t >> 6] = q;
  __syncthreads();
  const float rstd = rsqrtf((qs[0] + qs[1] + qs[2] + qs[3]) * (1.0f / 1024.0f) + 1e-5f);
  const float4 wv = *reinterpret_cast<const float4*>(w + t * 4);
  const float4 bv = *reinterpret_cast<const float4*>(b + t * 4);
  ushort4v o4;
  o4.x = f2bf(cx * rstd * wv.x + bv.x);
  o4.y = f2bf(cy * rstd * wv.y + bv.y);
  o4.z = f2bf(cz * rstd * wv.z + bv.z);
  o4.w = f2bf(cw * rstd * wv.w + bv.w);
  *reinterpret_cast<ushort4v*>(out + (size_t)row * 1024 + t * 4) = o4;
}

// ---------------- QKV weight pack: out[(mat*1024 + h*64 + d)][m] = W_mat[h][m][d], bf16 ----
__global__ __launch_bounds__(256) void conv_qkv_kernel(
    const float* __restrict__ WQ, const float* __restrict__ WK,
    const float* __restrict__ WV, unsigned short* __restrict__ out)
{
  __shared__ float t[32][33];
  const int mat_h = blockIdx.z;              // 0..47
  const int mat = mat_h >> 4, h = mat_h & 15;
  const float* W = (mat == 0 ? WQ : (mat == 1 ? WK : WV)) + (size_t)h * (1024 * 64);
  const int m0 = blockIdx.x * 32;
  const int d0 = blockIdx.y * 32;
  const int tx = threadIdx.x & 31, ty = threadIdx.x >> 5;
#pragma unroll
  for (int j = 0; j < 4; j++)
    t[ty + j * 8][tx] = W[(size_t)(m0 + ty + j * 8) * 64 + d0 + tx];
  __syncthreads();
  const size_t obase = (size_t)(mat * 1024 + h * 64 + d0);
#pragma unroll
  for (int j = 0; j < 4; j++)
    out[(obase + ty + j * 8) * 1024 + m0 + tx] = f2bf(t[tx][ty + j * 8]);
}

__global__ __launch_bounds__(256) void pack_bias_kernel(
    const float* __restrict__ bQ, const float* __restrict__ bK,
    const float* __restrict__ bV, float* __restrict__ out)
{
  const int i = blockIdx.x * 256 + threadIdx.x;  // 0..3071
  if (i < 1024) out[i] = bQ[i];
  else if (i < 2048) out[i] = bK[i - 1024];
  else if (i < 3072) out[i] = bV[i - 2048];
}

// ---------------- generic transpose+cast: in [R][C] f32 -> out [C][R] bf16 ----------------
__global__ __launch_bounds__(256) void transpose_cast_kernel(
    const float* __restrict__ in, unsigned short* __restrict__ out, int R, int C)
{
  __shared__ float t[32][33];
  const int c0 = blockIdx.x * 32, r0 = blockIdx.y * 32;
  const int tx = threadIdx.x & 31, ty = threadIdx.x >> 5;
#pragma unroll
  for (int j = 0; j < 4; j++)
    t[ty + j * 8][tx] = in[(size_t)(r0 + ty + j * 8) * C + c0 + tx];
  __syncthreads();
#pragma unroll
  for (int j = 0; j < 4; j++)
    out[(size_t)(c0 + ty + j * 8) * R + r0 + tx] = f2bf(t[tx][ty + j * 8]);
}

// ---------------- GEMM: C[M][N] = A[M][K] * Bt[N][K]^T, bf16 in, fused epilogue -----------
// R16: depth-3 LDS rotation + counted vmcnt, ONE raw s_barrier per K-step (same barrier
// count as R10). Buffer staged at iter t was last read at iter t-1 -> already protected
// by that iter's barrier (this is what R13's depth-2 lacked). vmcnt(L) proves my t+1
// loads landed; barrier publishes block-wide; t+2's loads STAY IN FLIGHT across it.
// LDS: BN=128 96KB (1 blk/CU — 8-phase precedent says intra-block pipelining suffices);
// BN=64 72KB (2 blk/CU unchanged — clean isolated test of the mechanism).
// EPI 0: bf16 out = acc+bias;  EPI 1: f32 out = acc+bias+resid;  EPI 2: bf16 = gelu(acc+bias)
template <int BN, int EPI, int WAVES>
__global__ __launch_bounds__(WAVES * 64) void gemm_kernel(
    const unsigned short* __restrict__ A, const unsigned short* __restrict__ Bt,
    void* Cout, const float* __restrict__ bias, const float* resid,
    int N, int K, int gx)
{
  constexpr int BM = 128, BK = 64;
  constexpr int NF = (BN * 2) / (WAVES * 16);        // 8w/128: 2; 8w/64: 1
  constexpr int CA = (BM / 8) / WAVES;               // A staging chunks per wave (2)
  constexpr int CB = (BN / 8) / WAVES;               // B staging chunks per wave (2 or 1)
  constexpr int L = CA + CB;                         // per-wave gload16 per stage (4 or 3)
  __shared__ __align__(16) unsigned short As[3][BM * BK];
  __shared__ __align__(16) unsigned short Bs[3][BN * BK];
  const int tid = threadIdx.x, lane = tid & 63, w = tid >> 6;
  const int nwg = gridDim.x;
  int id = blockIdx.x;
  id = (id & 7) * (nwg >> 3) + (id >> 3);     // bijective XCD swizzle (nwg % 8 == 0)
  const int bm = (id % gx) * BM, bn = (id / gx) * BN;

  const int l15 = lane & 15, hi = lane >> 4;
  const int arow = (w >> 2) * 64;
  const int brow = (w & 3) * (BN / 4);
  f32x4 acc[4][NF] = {};

  // staging: 8-row/1KB chunks; lane covers (row=lane>>3, blk=lane&7) of a 128B row.
  // source col pre-swizzled by involution blk ^= (row&7); reader XORs the same.
  const int srow = lane >> 3;
  const int scol = ((lane & 7) ^ srow) * 8;
  const unsigned short* Ag[CA];
  const unsigned short* Bg[CB];
#pragma unroll
  for (int it = 0; it < CA; it++)
    Ag[it] = A + (size_t)(bm + 8 * (it * WAVES + w) + srow) * K + scol;
#pragma unroll
  for (int it = 0; it < CB; it++)
    Bg[it] = Bt + (size_t)(bn + 8 * (it * WAVES + w) + srow) * K + scol;

  const int rsw = (l15 & 7) << 4;             // row-dependent byte XOR
  const int NT = K / BK;                      // 16 or 64 here (always >= 3)

  auto stage = [&](int k0, int buf) {
#pragma unroll
    for (int it = 0; it < CA; it++)
      gload16(Ag[it] + k0, &As[buf][(it * WAVES + w) * 512]);
#pragma unroll
    for (int it = 0; it < CB; it++)
      gload16(Bg[it] + k0, &Bs[buf][(it * WAVES + w) * 512]);
  };

#define VM_WAIT_L()                                                        \
  do {                                                                     \
    if constexpr (L == 4) asm volatile("s_waitcnt vmcnt(4)" ::: "memory"); \
    else                  asm volatile("s_waitcnt vmcnt(3)" ::: "memory"); \
  } while (0)

  // prologue: tiles 0,1 in flight; my tile-0 share resident, then publish via barrier
  stage(0, 0);
  stage(BK, 1);
  VM_WAIT_L();
  __builtin_amdgcn_s_barrier();
  asm volatile("" ::: "memory");

  for (int t = 0; t < NT; ++t) {
    const int cur = t % 3;
    if (t + 2 < NT) stage((t + 2) * BK, (t + 2) % 3);

    const char* Asb = (const char*)As[cur];
    const char* Bsb = (const char*)Bs[cur];
    bf16x8 af[2][4], bfr[2][NF];
#pragma unroll
    for (int kk = 0; kk < 2; kk++) {
      const int cb = kk * 64 + hi * 16;
#pragma unroll
      for (int mf = 0; mf < 4; mf++) {
        const int R = arow + mf * 16 + l15;
        af[kk][mf] = as_bf(*reinterpret_cast<const ushort8*>(Asb + R * (BK * 2) + (cb ^ rsw)));
      }
#pragma unroll
      for (int nf = 0; nf < NF; nf++) {
        const int R = brow + nf * 16 + l15;
        bfr[kk][nf] = as_bf(*reinterpret_cast<const ushort8*>(Bsb + R * (BK * 2) + (cb ^ rsw)));
      }
    }
#pragma unroll
    for (int kk = 0; kk < 2; kk++)
#pragma unroll
      for (int mf = 0; mf < 4; mf++)
#pragma unroll
        for (int nf = 0; nf < NF; nf++)
          acc[mf][nf] = __builtin_amdgcn_mfma_f32_16x16x32_bf16(af[kk][mf], bfr[kk][nf], acc[mf][nf], 0, 0, 0);

    if (t + 1 < NT) {
      asm volatile("s_waitcnt lgkmcnt(0)" ::: "memory");   // my reads of b[cur] done
      if (t + 2 < NT) VM_WAIT_L();                          // t+1 landed; t+2 in flight
      else asm volatile("s_waitcnt vmcnt(0)" ::: "memory"); // last prefetch drains
      __builtin_amdgcn_s_barrier();
      asm volatile("" ::: "memory");
    }
  }
#undef VM_WAIT_L

  const int row0 = bm + arow + 4 * hi;
  const int col0 = bn + brow + l15;
#pragma unroll
  for (int mf = 0; mf < 4; mf++) {
#pragma unroll
    for (int nf = 0; nf < NF; nf++) {
#pragma unroll
      for (int i = 0; i < 4; i++) {
        const int row = row0 + mf * 16 + i;
        const int col = col0 + nf * 16;
        float v = acc[mf][nf][i] + bias[col];
        if (EPI == 1) v += resid[(size_t)row * N + col];
        if (EPI == 2) v = gelu_f(v);
        if (EPI == 1) ((float*)Cout)[(size_t)row * N + col] = v;
        else          ((unsigned short*)Cout)[(size_t)row * N + col] = f2bf(v);
      }
    }
  }
}

// ---------------- causal flash attention, 64-row chunk pairs (R10 verbatim) ----------------
// Best of five structures (R10 109us; R11 un-pair 172us; R12 8-wave 160us; R14 KVBLK=128
// 170us — VGPR 140 + 46KB LDS crossed the occupancy cliff). This kernel is a sharp local
// optimum: 128 VGPR / 27.6KB LDS / 18.8% occ. DO NOT add registers (R4/R6/R14).
// DO NOT use __launch_bounds__ min-waves arg (R5: scratch spill, 3x slower).
__global__ __launch_bounds__(256) void attn_kernel(
    const unsigned short* __restrict__ qkv, unsigned short* __restrict__ zout)
{
  __shared__ __align__(16) unsigned short Ks[64 * 72];
  __shared__ __align__(16) unsigned short Vt[64 * 72];   // V^T, phys kv = kv ^ ((d>>3&7)<<3)
  __shared__ __align__(16) unsigned short Ps[4 * 16 * 72];
  const int tid = threadIdx.x, lane = tid & 63, w = tid >> 6;
  const int l15 = lane & 15, hi = lane >> 4, ko = hi * 8;
  const int j = blockIdx.x, bh = blockIdx.y;
  const int cA = j, cB = 31 - j;
  const size_t tok0 = (size_t)(bh >> 4) * 2048;
  const int h = bh & 15;
  const int qoff = h * 64, koff = 1024 + h * 64, voff = 2048 + h * 64;
  const int rowA = cA * 64 + w * 16;
  const int rowB = cB * 64 + w * 16;
  const float qscale = 0.125f * 1.44269504f;  // fold 1/sqrt(d) and log2(e) into Q

  bf16x8 qfA[2], qfB[2];
#pragma unroll
  for (int kf = 0; kf < 2; kf++) {
    qfA[kf] = scale8(*reinterpret_cast<const ushort8*>(qkv + (tok0 + rowA + l15) * 3072 + qoff + kf * 32 + ko), qscale);
    qfB[kf] = scale8(*reinterpret_cast<const ushort8*>(qkv + (tok0 + rowB + l15) * 3072 + qoff + kf * 32 + ko), qscale);
  }

  float mA[4], lA[4], mB[4], lB[4];
  f32x4 zA[4], zB[4];
#pragma unroll
  for (int i = 0; i < 4; i++) {
    mA[i] = -1e30f; lA[i] = 0.0f; mB[i] = -1e30f; lB[i] = 0.0f;
#pragma unroll
    for (int nf = 0; nf < 4; nf++) { zA[nf][i] = 0.0f; zB[nf][i] = 0.0f; }
  }

  unsigned short* Pw = Ps + w * (16 * 72);
  const int sr = tid >> 3, scol = (tid & 7) * 8;

  for (int kt = 0; kt <= cB; kt++) {
    __syncthreads();
#pragma unroll
    for (int it = 0; it < 2; it++) {
      const int rr = sr + it * 32;
      const size_t gb = (tok0 + kt * 64 + rr) * 3072;
      *reinterpret_cast<ushort8*>(&Ks[rr * 72 + scol]) =
          *reinterpret_cast<const ushort8*>(qkv + gb + koff + scol);
      ushort8 vv = *reinterpret_cast<const ushort8*>(qkv + gb + voff + scol);
#pragma unroll
      for (int jj = 0; jj < 8; jj++) {
        const int d = scol + jj;
        Vt[d * 72 + (rr ^ (((d >> 3) & 7) << 3))] = vv[jj];
      }
    }
    __syncthreads();

    bf16x8 kb[4][2], vb[4][2];
#pragma unroll
    for (int nf = 0; nf < 4; nf++)
#pragma unroll
      for (int kf = 0; kf < 2; kf++) {
        kb[nf][kf] = as_bf(*reinterpret_cast<const ushort8*>(&Ks[(nf * 16 + l15) * 72 + kf * 32 + ko]));
        const int d = nf * 16 + l15;
        vb[nf][kf] = as_bf(*reinterpret_cast<const ushort8*>(
            &Vt[d * 72 + ((kf * 32 + ko) ^ (((d >> 3) & 7) << 3))]));
      }

    const bool actA = (kt <= cA);

    f32x4 sA[4] = {}, sB[4] = {};
    __builtin_amdgcn_s_setprio(1);
#pragma unroll
    for (int nf = 0; nf < 4; nf++)
#pragma unroll
      for (int kf = 0; kf < 2; kf++) {
        if (actA) sA[nf] = __builtin_amdgcn_mfma_f32_16x16x32_bf16(qfA[kf], kb[nf][kf], sA[nf], 0, 0, 0);
        sB[nf] = __builtin_amdgcn_mfma_f32_16x16x32_bf16(qfB[kf], kb[nf][kf], sB[nf], 0, 0, 0);
      }
    __builtin_amdgcn_s_setprio(0);

    auto process = [&](f32x4* s, float* mrow, float* lrow, f32x4* accz, int rowbase, bool dm) {
#pragma unroll
      for (int i = 0; i < 4; i++) {
        const int rg = rowbase + 4 * hi + i;
        float mx = -1e30f;
#pragma unroll
        for (int nf = 0; nf < 4; nf++) {
          float v = s[nf][i];
          if (dm && (kt * 64 + nf * 16 + l15 > rg)) v = -1e30f;
          s[nf][i] = v;
          mx = fmaxf(mx, v);
        }
#pragma unroll
        for (int o = 1; o <= 8; o <<= 1) mx = fmaxf(mx, __shfl_xor(mx, o));
        const float mnew = fmaxf(mrow[i], mx);
        const float fct = exp2f(mrow[i] - mnew);
        mrow[i] = mnew;
        float rs = 0.0f;
#pragma unroll
        for (int nf = 0; nf < 4; nf++) {
          const float pv = exp2f(s[nf][i] - mnew);
          s[nf][i] = pv;
          rs += pv;
        }
#pragma unroll
        for (int o = 1; o <= 8; o <<= 1) rs += __shfl_xor(rs, o);
        lrow[i] = lrow[i] * fct + rs;
#pragma unroll
        for (int nf = 0; nf < 4; nf++) accz[nf][i] *= fct;
      }
      // P -> LDS, col swizzled by row-group (hi)
#pragma unroll
      for (int i = 0; i < 4; i++)
#pragma unroll
        for (int nf = 0; nf < 4; nf++)
          Pw[(4 * hi + i) * 72 + ((nf * 16 + l15) ^ (hi << 3))] = f2bf_rn(s[nf][i]);
      // PV
#pragma unroll
      for (int kf = 0; kf < 2; kf++) {
        const bf16x8 pa = as_bf(*reinterpret_cast<const ushort8*>(
            &Pw[l15 * 72 + ((kf * 32 + ko) ^ (((l15 >> 2) & 3) << 3))]));
        __builtin_amdgcn_s_setprio(1);
#pragma unroll
        for (int nf = 0; nf < 4; nf++)
          accz[nf] = __builtin_amdgcn_mfma_f32_16x16x32_bf16(pa, vb[nf][kf], accz[nf], 0, 0, 0);
        __builtin_amdgcn_s_setprio(0);
      }
    };

    if (actA) process(sA, mA, lA, zA, rowA, kt >= cA);
    process(sB, mB, lB, zB, rowB, kt >= cB);
  }

  auto wb = [&](float* lrow, f32x4* accz, int rowbase) {
#pragma unroll
    for (int i = 0; i < 4; i++) {
      const float inv = 1.0f / lrow[i];
      const int srow = rowbase + 4 * hi + i;
#pragma unroll
      for (int nf = 0; nf < 4; nf++)
        zout[(tok0 + srow) * 1024 + h * 64 + nf * 16 + l15] = f2bf_rn(accz[nf][i] * inv);
    }
  };
  wb(lA, zA, rowA);
  wb(lB, zB, rowB);
}

// ---------------- host-side launch ----------------
extern "C" void kernel_launch(void* const* d_in, const int* in_sizes, int n_in,
                              void* d_out, int out_size, void* d_ws, size_t ws_size,
                              hipStream_t stream)
{
  const float* x    = (const float*)d_in[0];
  const float* ln1w = (const float*)d_in[1];
  const float* ln1b = (const float*)d_in[2];
  const float* WQ   = (const float*)d_in[3];
  const float* WK   = (const float*)d_in[4];
  const float* WV   = (const float*)d_in[5];
  const float* WO   = (const float*)d_in[6];
  const float* bQ   = (const float*)d_in[7];
  const float* bK   = (const float*)d_in[8];
  const float* bV   = (const float*)d_in[9];
  const float* bO   = (const float*)d_in[10];
  const float* ln2w = (const float*)d_in[11];
  const float* ln2b = (const float*)d_in[12];
  const float* Win  = (const float*)d_in[13];
  const float* bin  = (const float*)d_in[14];
  const float* Wout = (const float*)d_in[15];
  const float* bout = (const float*)d_in[16];
  float* out = (float*)d_out;

  char* ws = (char*)d_ws;
  unsigned short* bufA   = (unsigned short*)ws;                        // 32MB: qkv -> h
  unsigned short* bufB   = (unsigned short*)(ws + (size_t)(32 << 20)); // 8MB: xn1 -> z -> xn2
  unsigned short* bufC   = (unsigned short*)(ws + (size_t)(40 << 20)); // 8MB: bf16 B^T weights
  float*          biasQKV = (float*)(ws + (size_t)(48 << 20));         // 12KB

  // LN1 -> xn1 (bf16)
  ln_kernel<<<4096, 256, 0, stream>>>(x, ln1w, ln1b, bufB);
  // QKV weights -> B^T bf16 [3072][1024] + packed bias
  conv_qkv_kernel<<<dim3(32, 2, 48), 256, 0, stream>>>(WQ, WK, WV, bufC);
  pack_bias_kernel<<<12, 256, 0, stream>>>(bQ, bK, bV, biasQKV);
  // QKV projection: qkv = xn1 @ Wqkv + b  (bf16)  grid 32x24 = 768, 8-wave
  gemm_kernel<128, 0, 8><<<768, 512, 0, stream>>>(bufB, bufC, bufA, biasQKV, nullptr, 3072, 1024, 32);
  // causal attention -> z (bf16)  grid (16 pairs, 32 bh), 4-wave (R10 config)
  attn_kernel<<<dim3(16, 32), 256, 0, stream>>>(bufA, bufB);
  // O-projection weights -> B^T [1024][1024]
  transpose_cast_kernel<<<dim3(32, 32), 256, 0, stream>>>(WO, bufC, 1024, 1024);
  // resid = z @ W_O + b_O + x  (f32 into d_out)  grid 512 (BN=64), 8-wave
  gemm_kernel<64, 1, 8><<<512, 512, 0, stream>>>(bufB, bufC, out, bO, x, 1024, 1024, 32);
  // LN2 -> xn2 (bf16)
  ln_kernel<<<4096, 256, 0, stream>>>(out, ln2w, ln2b, bufB);
  // W_in -> B^T [4096][1024]
  transpose_cast_kernel<<<dim3(128, 32), 256, 0, stream>>>(Win, bufC, 1024, 4096);
  // h = gelu(xn2 @ W_in + b_in)  (bf16)  grid 32x32 = 1024, 8-wave
  gemm_kernel<128, 2, 8><<<1024, 512, 0, stream>>>(bufB, bufC, bufA, bin, nullptr, 4096, 1024, 32);
  // W_out -> B^T [1024][4096]
  transpose_cast_kernel<<<dim3(32, 128), 256, 0, stream>>>(Wout, bufC, 4096, 1024);
  // out = resid + h @ W_out + b_out  (f32, resid in-place)  grid 512 (BN=64), 8-wave
  gemm_kernel<64, 1, 8><<<512, 512, 0, stream>>>(bufA, bufC, out, bout, out, 1024, 4096, 32);
}

// Round 17
// 292.267 us; speedup vs baseline: 1.2180x; 1.2180x over previous
//
#include <hip/hip_runtime.h>

typedef __attribute__((ext_vector_type(4))) float f32x4;
typedef __attribute__((ext_vector_type(8))) __bf16 bf16x8;
typedef __attribute__((ext_vector_type(8))) unsigned short ushort8;
typedef __attribute__((ext_vector_type(4))) unsigned short ushort4v;

union UBF8 { ushort8 u; bf16x8 b; };
static __device__ __forceinline__ bf16x8 as_bf(ushort8 v) { UBF8 x; x.u = v; return x.b; }

// native f32 -> bf16 (RNE)
static __device__ __forceinline__ unsigned short f2bf(float f) {
  union { __bf16 h; unsigned short u; } v; v.h = (__bf16)f; return v.u;
}

// manual RNE (attn: exact R3/R10 codegen, 128 VGPR)
static __device__ __forceinline__ unsigned short f2bf_rn(float f) {
  union { float f; unsigned u; } v; v.f = f;
  unsigned r = v.u + 0x7fffu + ((v.u >> 16) & 1u);
  return (unsigned short)(r >> 16);
}

static __device__ __forceinline__ bf16x8 scale8(ushort8 u, float c) {
  ushort8 r;
#pragma unroll
  for (int j = 0; j < 8; j++) {
    union { unsigned u; float f; } t; t.u = ((unsigned)u[j]) << 16;
    r[j] = f2bf_rn(t.f * c);
  }
  return as_bf(r);
}

static __device__ __forceinline__ float gelu_f(float x) {
  return 0.5f * x * (1.0f + erff(x * 0.70710678118654752f));
}

typedef const __attribute__((address_space(1))) void* gas_p;
typedef __attribute__((address_space(3))) void* las_p;
static __device__ __forceinline__ void gload16(const void* g, void* l) {
  __builtin_amdgcn_global_load_lds((gas_p)g, (las_p)l, 16, 0, 0);
}

// ---------------- LayerNorm: fp32 in -> bf16 out, one row (1024) per block ----------------
__global__ __launch_bounds__(256) void ln_kernel(
    const float* __restrict__ in, const float* __restrict__ w,
    const float* __restrict__ b, unsigned short* __restrict__ out)
{
  const int row = blockIdx.x, t = threadIdx.x;
  const float4 v = *reinterpret_cast<const float4*>(in + (size_t)row * 1024 + t * 4);
  float s = v.x + v.y + v.z + v.w;
#pragma unroll
  for (int o = 32; o >= 1; o >>= 1) s += __shfl_xor(s, o);
  __shared__ float ps[4], qs[4];
  if ((t & 63) == 0) ps[t >> 6] = s;
  __syncthreads();
  const float mean = (ps[0] + ps[1] + ps[2] + ps[3]) * (1.0f / 1024.0f);
  const float cx = v.x - mean, cy = v.y - mean, cz = v.z - mean, cw = v.w - mean;
  float q = cx * cx + cy * cy + cz * cz + cw * cw;
#pragma unroll
  for (int o = 32; o >= 1; o >>= 1) q += __shfl_xor(q, o);
  if ((t & 63) == 0) qs[t >> 6] = q;
  __syncthreads();
  const float rstd = rsqrtf((qs[0] + qs[1] + qs[2] + qs[3]) * (1.0f / 1024.0f) + 1e-5f);
  const float4 wv = *reinterpret_cast<const float4*>(w + t * 4);
  const float4 bv = *reinterpret_cast<const float4*>(b + t * 4);
  ushort4v o4;
  o4.x = f2bf(cx * rstd * wv.x + bv.x);
  o4.y = f2bf(cy * rstd * wv.y + bv.y);
  o4.z = f2bf(cz * rstd * wv.z + bv.z);
  o4.w = f2bf(cw * rstd * wv.w + bv.w);
  *reinterpret_cast<ushort4v*>(out + (size_t)row * 1024 + t * 4) = o4;
}

// ---------------- QKV weight pack: out[(mat*1024 + h*64 + d)][m] = W_mat[h][m][d], bf16 ----
__global__ __launch_bounds__(256) void conv_qkv_kernel(
    const float* __restrict__ WQ, const float* __restrict__ WK,
    const float* __restrict__ WV, unsigned short* __restrict__ out)
{
  __shared__ float t[32][33];
  const int mat_h = blockIdx.z;              // 0..47
  const int mat = mat_h >> 4, h = mat_h & 15;
  const float* W = (mat == 0 ? WQ : (mat == 1 ? WK : WV)) + (size_t)h * (1024 * 64);
  const int m0 = blockIdx.x * 32;
  const int d0 = blockIdx.y * 32;
  const int tx = threadIdx.x & 31, ty = threadIdx.x >> 5;
#pragma unroll
  for (int j = 0; j < 4; j++)
    t[ty + j * 8][tx] = W[(size_t)(m0 + ty + j * 8) * 64 + d0 + tx];
  __syncthreads();
  const size_t obase = (size_t)(mat * 1024 + h * 64 + d0);
#pragma unroll
  for (int j = 0; j < 4; j++)
    out[(obase + ty + j * 8) * 1024 + m0 + tx] = f2bf(t[tx][ty + j * 8]);
}

__global__ __launch_bounds__(256) void pack_bias_kernel(
    const float* __restrict__ bQ, const float* __restrict__ bK,
    const float* __restrict__ bV, float* __restrict__ out)
{
  const int i = blockIdx.x * 256 + threadIdx.x;  // 0..3071
  if (i < 1024) out[i] = bQ[i];
  else if (i < 2048) out[i] = bK[i - 1024];
  else if (i < 3072) out[i] = bV[i - 2048];
}

// ---------------- generic transpose+cast: in [R][C] f32 -> out [C][R] bf16 ----------------
__global__ __launch_bounds__(256) void transpose_cast_kernel(
    const float* __restrict__ in, unsigned short* __restrict__ out, int R, int C)
{
  __shared__ float t[32][33];
  const int c0 = blockIdx.x * 32, r0 = blockIdx.y * 32;
  const int tx = threadIdx.x & 31, ty = threadIdx.x >> 5;
#pragma unroll
  for (int j = 0; j < 4; j++)
    t[ty + j * 8][tx] = in[(size_t)(r0 + ty + j * 8) * C + c0 + tx];
  __syncthreads();
#pragma unroll
  for (int j = 0; j < 4; j++)
    out[(size_t)(c0 + ty + j * 8) * R + r0 + tx] = f2bf(t[tx][ty + j * 8]);
}

// ---------------- GEMM: C[M][N] = A[M][K] * Bt[N][K]^T, bf16 in, fused epilogue -----------
// R10-benched version (best of 6 variants). BM=128, BK=64, WAVES=8, 2-phase dbuf,
// ONE __syncthreads per K-step. Measured-dead-ends: BK=32 (R8, +barriers), depth-2
// counted-vmcnt (R13, +barrier), depth-3 96KB (R16, -occupancy). The path past ~690 TF
// is the full 8-phase 256-square co-designed rewrite, not a graft on this structure.
// Linear LDS dest + pre-swizzled global source (rule #21), swizzled ds_read.
// EPI 0: bf16 out = acc+bias;  EPI 1: f32 out = acc+bias+resid;  EPI 2: bf16 = gelu(acc+bias)
template <int BN, int EPI, int WAVES>
__global__ __launch_bounds__(WAVES * 64) void gemm_kernel(
    const unsigned short* __restrict__ A, const unsigned short* __restrict__ Bt,
    void* Cout, const float* __restrict__ bias, const float* resid,
    int N, int K, int gx)
{
  constexpr int BM = 128, BK = 64;
  constexpr int NF = (BN * 2) / (WAVES * 16);        // 8w/128: 2; 8w/64: 1
  constexpr int CA = (BM / 8) / WAVES;               // A staging chunks per wave
  constexpr int CB = (BN / 8) / WAVES;               // B staging chunks per wave
  __shared__ __align__(16) unsigned short As[2][BM * BK];
  __shared__ __align__(16) unsigned short Bs[2][BN * BK];
  const int tid = threadIdx.x, lane = tid & 63, w = tid >> 6;
  const int nwg = gridDim.x;
  int id = blockIdx.x;
  id = (id & 7) * (nwg >> 3) + (id >> 3);     // bijective XCD swizzle (nwg % 8 == 0)
  const int bm = (id % gx) * BM, bn = (id / gx) * BN;

  const int l15 = lane & 15, hi = lane >> 4;
  const int arow = (w >> 2) * 64;
  const int brow = (w & 3) * (BN / 4);
  f32x4 acc[4][NF] = {};

  // staging: 8-row/1KB chunks; lane covers (row=lane>>3, blk=lane&7) of a 128B row.
  // source col pre-swizzled by involution blk ^= (row&7); reader XORs the same.
  const int srow = lane >> 3;
  const int scol = ((lane & 7) ^ srow) * 8;
  const unsigned short* Ag[CA];
  const unsigned short* Bg[CB];
#pragma unroll
  for (int it = 0; it < CA; it++)
    Ag[it] = A + (size_t)(bm + 8 * (it * WAVES + w) + srow) * K + scol;
#pragma unroll
  for (int it = 0; it < CB; it++)
    Bg[it] = Bt + (size_t)(bn + 8 * (it * WAVES + w) + srow) * K + scol;

  const int rsw = (l15 & 7) << 4;             // row-dependent byte XOR
  const int NT = K / BK;

  auto stage = [&](int k0, int buf) {
#pragma unroll
    for (int it = 0; it < CA; it++)
      gload16(Ag[it] + k0, &As[buf][(it * WAVES + w) * 512]);
#pragma unroll
    for (int it = 0; it < CB; it++)
      gload16(Bg[it] + k0, &Bs[buf][(it * WAVES + w) * 512]);
  };

  stage(0, 0);
  __syncthreads();
  int cur = 0;

  for (int t = 0; t < NT; ++t) {
    if (t + 1 < NT) stage((t + 1) * BK, cur ^ 1);

    const char* Asb = (const char*)As[cur];
    const char* Bsb = (const char*)Bs[cur];
    bf16x8 af[2][4], bfr[2][NF];
#pragma unroll
    for (int kk = 0; kk < 2; kk++) {
      const int cb = kk * 64 + hi * 16;
#pragma unroll
      for (int mf = 0; mf < 4; mf++) {
        const int R = arow + mf * 16 + l15;
        af[kk][mf] = as_bf(*reinterpret_cast<const ushort8*>(Asb + R * (BK * 2) + (cb ^ rsw)));
      }
#pragma unroll
      for (int nf = 0; nf < NF; nf++) {
        const int R = brow + nf * 16 + l15;
        bfr[kk][nf] = as_bf(*reinterpret_cast<const ushort8*>(Bsb + R * (BK * 2) + (cb ^ rsw)));
      }
    }
#pragma unroll
    for (int kk = 0; kk < 2; kk++)
#pragma unroll
      for (int mf = 0; mf < 4; mf++)
#pragma unroll
        for (int nf = 0; nf < NF; nf++)
          acc[mf][nf] = __builtin_amdgcn_mfma_f32_16x16x32_bf16(af[kk][mf], bfr[kk][nf], acc[mf][nf], 0, 0, 0);

    __syncthreads();
    cur ^= 1;
  }

  const int row0 = bm + arow + 4 * hi;
  const int col0 = bn + brow + l15;
#pragma unroll
  for (int mf = 0; mf < 4; mf++) {
#pragma unroll
    for (int nf = 0; nf < NF; nf++) {
#pragma unroll
      for (int i = 0; i < 4; i++) {
        const int row = row0 + mf * 16 + i;
        const int col = col0 + nf * 16;
        float v = acc[mf][nf][i] + bias[col];
        if (EPI == 1) v += resid[(size_t)row * N + col];
        if (EPI == 2) v = gelu_f(v);
        if (EPI == 1) ((float*)Cout)[(size_t)row * N + col] = v;
        else          ((unsigned short*)Cout)[(size_t)row * N + col] = f2bf(v);
      }
    }
  }
}

// ---------------- causal flash attention, 64-row chunk pairs (R10 verbatim) ----------------
// Best of five structures (R10 109us; R11 un-pair 172us; R12 8-wave 160us; R14 KVBLK=128
// 170us — VGPR 140 + 46KB LDS crossed the occupancy cliff). This kernel is a sharp local
// optimum: 128 VGPR / 27.6KB LDS / 18.8% occ. DO NOT add registers (R4/R6/R14).
// DO NOT use __launch_bounds__ min-waves arg (R5: scratch spill, 3x slower).
__global__ __launch_bounds__(256) void attn_kernel(
    const unsigned short* __restrict__ qkv, unsigned short* __restrict__ zout)
{
  __shared__ __align__(16) unsigned short Ks[64 * 72];
  __shared__ __align__(16) unsigned short Vt[64 * 72];   // V^T, phys kv = kv ^ ((d>>3&7)<<3)
  __shared__ __align__(16) unsigned short Ps[4 * 16 * 72];
  const int tid = threadIdx.x, lane = tid & 63, w = tid >> 6;
  const int l15 = lane & 15, hi = lane >> 4, ko = hi * 8;
  const int j = blockIdx.x, bh = blockIdx.y;
  const int cA = j, cB = 31 - j;
  const size_t tok0 = (size_t)(bh >> 4) * 2048;
  const int h = bh & 15;
  const int qoff = h * 64, koff = 1024 + h * 64, voff = 2048 + h * 64;
  const int rowA = cA * 64 + w * 16;
  const int rowB = cB * 64 + w * 16;
  const float qscale = 0.125f * 1.44269504f;  // fold 1/sqrt(d) and log2(e) into Q

  bf16x8 qfA[2], qfB[2];
#pragma unroll
  for (int kf = 0; kf < 2; kf++) {
    qfA[kf] = scale8(*reinterpret_cast<const ushort8*>(qkv + (tok0 + rowA + l15) * 3072 + qoff + kf * 32 + ko), qscale);
    qfB[kf] = scale8(*reinterpret_cast<const ushort8*>(qkv + (tok0 + rowB + l15) * 3072 + qoff + kf * 32 + ko), qscale);
  }

  float mA[4], lA[4], mB[4], lB[4];
  f32x4 zA[4], zB[4];
#pragma unroll
  for (int i = 0; i < 4; i++) {
    mA[i] = -1e30f; lA[i] = 0.0f; mB[i] = -1e30f; lB[i] = 0.0f;
#pragma unroll
    for (int nf = 0; nf < 4; nf++) { zA[nf][i] = 0.0f; zB[nf][i] = 0.0f; }
  }

  unsigned short* Pw = Ps + w * (16 * 72);
  const int sr = tid >> 3, scol = (tid & 7) * 8;

  for (int kt = 0; kt <= cB; kt++) {
    __syncthreads();
#pragma unroll
    for (int it = 0; it < 2; it++) {
      const int rr = sr + it * 32;
      const size_t gb = (tok0 + kt * 64 + rr) * 3072;
      *reinterpret_cast<ushort8*>(&Ks[rr * 72 + scol]) =
          *reinterpret_cast<const ushort8*>(qkv + gb + koff + scol);
      ushort8 vv = *reinterpret_cast<const ushort8*>(qkv + gb + voff + scol);
#pragma unroll
      for (int jj = 0; jj < 8; jj++) {
        const int d = scol + jj;
        Vt[d * 72 + (rr ^ (((d >> 3) & 7) << 3))] = vv[jj];
      }
    }
    __syncthreads();

    bf16x8 kb[4][2], vb[4][2];
#pragma unroll
    for (int nf = 0; nf < 4; nf++)
#pragma unroll
      for (int kf = 0; kf < 2; kf++) {
        kb[nf][kf] = as_bf(*reinterpret_cast<const ushort8*>(&Ks[(nf * 16 + l15) * 72 + kf * 32 + ko]));
        const int d = nf * 16 + l15;
        vb[nf][kf] = as_bf(*reinterpret_cast<const ushort8*>(
            &Vt[d * 72 + ((kf * 32 + ko) ^ (((d >> 3) & 7) << 3))]));
      }

    const bool actA = (kt <= cA);

    f32x4 sA[4] = {}, sB[4] = {};
    __builtin_amdgcn_s_setprio(1);
#pragma unroll
    for (int nf = 0; nf < 4; nf++)
#pragma unroll
      for (int kf = 0; kf < 2; kf++) {
        if (actA) sA[nf] = __builtin_amdgcn_mfma_f32_16x16x32_bf16(qfA[kf], kb[nf][kf], sA[nf], 0, 0, 0);
        sB[nf] = __builtin_amdgcn_mfma_f32_16x16x32_bf16(qfB[kf], kb[nf][kf], sB[nf], 0, 0, 0);
      }
    __builtin_amdgcn_s_setprio(0);

    auto process = [&](f32x4* s, float* mrow, float* lrow, f32x4* accz, int rowbase, bool dm) {
#pragma unroll
      for (int i = 0; i < 4; i++) {
        const int rg = rowbase + 4 * hi + i;
        float mx = -1e30f;
#pragma unroll
        for (int nf = 0; nf < 4; nf++) {
          float v = s[nf][i];
          if (dm && (kt * 64 + nf * 16 + l15 > rg)) v = -1e30f;
          s[nf][i] = v;
          mx = fmaxf(mx, v);
        }
#pragma unroll
        for (int o = 1; o <= 8; o <<= 1) mx = fmaxf(mx, __shfl_xor(mx, o));
        const float mnew = fmaxf(mrow[i], mx);
        const float fct = exp2f(mrow[i] - mnew);
        mrow[i] = mnew;
        float rs = 0.0f;
#pragma unroll
        for (int nf = 0; nf < 4; nf++) {
          const float pv = exp2f(s[nf][i] - mnew);
          s[nf][i] = pv;
          rs += pv;
        }
#pragma unroll
        for (int o = 1; o <= 8; o <<= 1) rs += __shfl_xor(rs, o);
        lrow[i] = lrow[i] * fct + rs;
#pragma unroll
        for (int nf = 0; nf < 4; nf++) accz[nf][i] *= fct;
      }
      // P -> LDS, col swizzled by row-group (hi)
#pragma unroll
      for (int i = 0; i < 4; i++)
#pragma unroll
        for (int nf = 0; nf < 4; nf++)
          Pw[(4 * hi + i) * 72 + ((nf * 16 + l15) ^ (hi << 3))] = f2bf_rn(s[nf][i]);
      // PV
#pragma unroll
      for (int kf = 0; kf < 2; kf++) {
        const bf16x8 pa = as_bf(*reinterpret_cast<const ushort8*>(
            &Pw[l15 * 72 + ((kf * 32 + ko) ^ (((l15 >> 2) & 3) << 3))]));
        __builtin_amdgcn_s_setprio(1);
#pragma unroll
        for (int nf = 0; nf < 4; nf++)
          accz[nf] = __builtin_amdgcn_mfma_f32_16x16x32_bf16(pa, vb[nf][kf], accz[nf], 0, 0, 0);
        __builtin_amdgcn_s_setprio(0);
      }
    };

    if (actA) process(sA, mA, lA, zA, rowA, kt >= cA);
    process(sB, mB, lB, zB, rowB, kt >= cB);
  }

  auto wb = [&](float* lrow, f32x4* accz, int rowbase) {
#pragma unroll
    for (int i = 0; i < 4; i++) {
      const float inv = 1.0f / lrow[i];
      const int srow = rowbase + 4 * hi + i;
#pragma unroll
      for (int nf = 0; nf < 4; nf++)
        zout[(tok0 + srow) * 1024 + h * 64 + nf * 16 + l15] = f2bf_rn(accz[nf][i] * inv);
    }
  };
  wb(lA, zA, rowA);
  wb(lB, zB, rowB);
}

// ---------------- host-side launch ----------------
extern "C" void kernel_launch(void* const* d_in, const int* in_sizes, int n_in,
                              void* d_out, int out_size, void* d_ws, size_t ws_size,
                              hipStream_t stream)
{
  const float* x    = (const float*)d_in[0];
  const float* ln1w = (const float*)d_in[1];
  const float* ln1b = (const float*)d_in[2];
  const float* WQ   = (const float*)d_in[3];
  const float* WK   = (const float*)d_in[4];
  const float* WV   = (const float*)d_in[5];
  const float* WO   = (const float*)d_in[6];
  const float* bQ   = (const float*)d_in[7];
  const float* bK   = (const float*)d_in[8];
  const float* bV   = (const float*)d_in[9];
  const float* bO   = (const float*)d_in[10];
  const float* ln2w = (const float*)d_in[11];
  const float* ln2b = (const float*)d_in[12];
  const float* Win  = (const float*)d_in[13];
  const float* bin  = (const float*)d_in[14];
  const float* Wout = (const float*)d_in[15];
  const float* bout = (const float*)d_in[16];
  float* out = (float*)d_out;

  char* ws = (char*)d_ws;
  unsigned short* bufA   = (unsigned short*)ws;                        // 32MB: qkv -> h
  unsigned short* bufB   = (unsigned short*)(ws + (size_t)(32 << 20)); // 8MB: xn1 -> z -> xn2
  unsigned short* bufC   = (unsigned short*)(ws + (size_t)(40 << 20)); // 8MB: bf16 B^T weights
  float*          biasQKV = (float*)(ws + (size_t)(48 << 20));         // 12KB

  // LN1 -> xn1 (bf16)
  ln_kernel<<<4096, 256, 0, stream>>>(x, ln1w, ln1b, bufB);
  // QKV weights -> B^T bf16 [3072][1024] + packed bias
  conv_qkv_kernel<<<dim3(32, 2, 48), 256, 0, stream>>>(WQ, WK, WV, bufC);
  pack_bias_kernel<<<12, 256, 0, stream>>>(bQ, bK, bV, biasQKV);
  // QKV projection: qkv = xn1 @ Wqkv + b  (bf16)  grid 32x24 = 768, 8-wave
  gemm_kernel<128, 0, 8><<<768, 512, 0, stream>>>(bufB, bufC, bufA, biasQKV, nullptr, 3072, 1024, 32);
  // causal attention -> z (bf16)  grid (16 pairs, 32 bh), 4-wave (R10 config)
  attn_kernel<<<dim3(16, 32), 256, 0, stream>>>(bufA, bufB);
  // O-projection weights -> B^T [1024][1024]
  transpose_cast_kernel<<<dim3(32, 32), 256, 0, stream>>>(WO, bufC, 1024, 1024);
  // resid = z @ W_O + b_O + x  (f32 into d_out)  grid 512 (BN=64), 8-wave
  gemm_kernel<64, 1, 8><<<512, 512, 0, stream>>>(bufB, bufC, out, bO, x, 1024, 1024, 32);
  // LN2 -> xn2 (bf16)
  ln_kernel<<<4096, 256, 0, stream>>>(out, ln2w, ln2b, bufB);
  // W_in -> B^T [4096][1024]
  transpose_cast_kernel<<<dim3(128, 32), 256, 0, stream>>>(Win, bufC, 1024, 4096);
  // h = gelu(xn2 @ W_in + b_in)  (bf16)  grid 32x32 = 1024, 8-wave
  gemm_kernel<128, 2, 8><<<1024, 512, 0, stream>>>(bufB, bufC, bufA, bin, nullptr, 4096, 1024, 32);
  // W_out -> B^T [1024][4096]
  transpose_cast_kernel<<<dim3(32, 128), 256, 0, stream>>>(Wout, bufC, 4096, 1024);
  // out = resid + h @ W_out + b_out  (f32, resid in-place)  grid 512 (BN=64), 8-wave
  gemm_kernel<64, 1, 8><<<512, 512, 0, stream>>>(bufA, bufC, out, bout, out, 1024, 4096, 32);
}